// Round 3
// baseline (302.214 us; speedup 1.0000x reference)
//
#include <hip/hip_runtime.h>

// Reference numpy/jnp math is UNFUSED IEEE f32 — disable FMA contraction so
// the catastrophically-cancelled det (compared against EPS=1e-7) and the
// 1/det-scaled shifts are bit-identical to the reference.
#pragma clang fp contract(off)

// Problem constants (from setup_inputs): B=2, C=4, D=6, H=512, W=512, f32.
constexpr int B_ = 2, C_ = 4, D_ = 6, H_ = 512, W_ = 512;
constexpr int HW_  = H_ * W_;        // 262144
constexpr int DHW_ = D_ * HW_;       // 1572864
constexpr int BC_  = B_ * C_;        // 8
constexpr int TOT_ = BC_ * DHW_;     // 12582912
constexpr int NWAVES_ = TOT_ / 256;  // 49152 groups of 256 voxels
constexpr size_t BITMAP_BYTES_ = (size_t)NWAVES_ * 4 * 8;  // 1.5 MB

#define EPS_ 1e-7f
#define MAX_SHIFT_ 0.6f
#define BONUS_ 10.0f
#define N_ITERS_ 5

// ---------------------------------------------------------------------------
// 3x3x3 quadratic-fit Cramer solve; p points at the (interior) center voxel.
// Op ordering mirrors the reference exactly (f32, no contraction).
__device__ __forceinline__ void solve3(const float* __restrict__ p,
                                       float& sx, float& sy, float& ss,
                                       float& gds, bool& sol)
{
    #pragma clang fp contract(off)
    float c    = p[0];
    float xp   = p[1],          xm   = p[-1];
    float yp   = p[W_],         ym   = p[-W_];
    float spv  = p[HW_],        smv  = p[-HW_];
    float xpyp = p[W_ + 1],     xmyp = p[W_ - 1];
    float xpym = p[-W_ + 1],    xmym = p[-W_ - 1];
    float xpsp = p[HW_ + 1],    xmsp = p[HW_ - 1];
    float xpsm = p[-HW_ + 1],   xmsm = p[-HW_ - 1];
    float ypsp = p[HW_ + W_],   ymsp = p[HW_ - W_];
    float ypsm = p[-HW_ + W_],  ymsm = p[-HW_ - W_];

    float gx = 0.5f * (xp - xm);
    float gy = 0.5f * (yp - ym);
    float gs = 0.5f * (spv - smv);
    float dxx = xp - 2.0f * c + xm;
    float dyy = yp - 2.0f * c + ym;
    float dss = spv - 2.0f * c + smv;
    float dxy = 0.25f * (xpyp - xmyp - xpym + xmym);
    float dxs = 0.25f * (xpsp - xmsp - xpsm + xmsm);
    float dys = 0.25f * (ypsp - ymsp - ypsm + ymsm);

    float cf00 = dyy * dss - dys * dys;
    float cf01 = dxy * dss - dys * dxs;
    float cf02 = dxy * dys - dyy * dxs;
    float det  = dxx * cf00 - dxy * cf01 + dxs * cf02;
    sol = fabsf(det) > EPS_;
    float sd = sol ? det : 1.0f;
    float r0 = -gx, r1 = -gy, r2 = -gs;
    sx = (r0 * cf00 - dxy * (r1 * dss - dys * r2) + dxs * (r1 * dys - dyy * r2)) / sd;
    sy = (dxx * (r1 * dss - dys * r2) - r0 * cf01 + dxs * (dxy * r2 - r1 * dxs)) / sd;
    ss = (dxx * (dyy * r2 - r1 * dys) - dxy * (dxy * r2 - r1 * dxs) + r0 * cf02) / sd;
    gds = gx * sx + gy * sy + gs * ss;
}

// Full reference walk + output write for one seed voxel. Scalar stores.
__device__ __forceinline__ void walk_and_write(const float* __restrict__ x,
                                               float* __restrict__ out, int idx)
{
    #pragma clang fp contract(off)
    int w  = idx & (W_ - 1);
    int h  = (idx >> 9) & (H_ - 1);
    int t  = idx >> 18;
    int d  = t % D_;
    int bc = t / D_;
    int sp = idx - bc * DHW_;
    const float* xb = x + bc * DHW_;
    float xc = x[idx];

    int dd = 0, dh = 0, dwo = 0;
    bool valid = true;
    float shx = 0.0f, shy = 0.0f, shs = 0.0f, gk = 0.0f;

    #pragma unroll 1
    for (int it = 0; it < N_ITERS_; ++it) {
        int di = min(max(d + dd, 1), D_ - 2);
        int hi = min(max(h + dh, 1), H_ - 2);
        int wi = min(max(w + dwo, 1), W_ - 2);
        const float* p = xb + di * HW_ + hi * W_ + wi;

        float sx, sy, ssv, gds; bool sol;
        solve3(p, sx, sy, ssv, gds, sol);

        valid = valid && sol;
        float vf = valid ? 1.0f : 0.0f;
        shx = sx * vf;
        shy = sy * vf;
        shs = ssv * vf;
        gk  = gds * vf;

        int stx = (shx > MAX_SHIFT_) ? 1 : ((shx < -MAX_SHIFT_) ? -1 : 0);
        int sty = (shy > MAX_SHIFT_) ? 1 : ((shy < -MAX_SHIFT_) ? -1 : 0);
        int sts = (shs > MAX_SHIFT_) ? 1 : ((shs < -MAX_SHIFT_) ? -1 : 0);
        dwo += stx;
        dh  += sty;
        dd  += sts;
        valid = valid && (abs(dd) <= 1) && (abs(dh) <= 1) && (abs(dwo) <= 1);
    }

    int di = min(max(d + dd, 1), D_ - 2);
    int hi = min(max(h + dh, 1), H_ - 2);
    int wi = min(max(w + dwo, 1), W_ - 2);
    float cur = xb[di * HW_ + hi * W_ + wi];

    float refined = valid ? (cur + 0.5f * gk) : xc;
    float yv = refined + BONUS_;               // nms_mask true at seeds
    float cs = valid ? ((float)(d + dd) + shs) : (float)d;
    float cx = valid ? ((float)(w + dwo) + shx) : (float)w;
    float cy = valid ? ((float)(h + dh) + shy) : (float)h;

    out[(bc * 3 + 0) * DHW_ + sp] = cs;
    out[(bc * 3 + 1) * DHW_ + sp] = cx;
    out[(bc * 3 + 2) * DHW_ + sp] = cy;
    out[BC_ * 3 * DHW_ + idx]     = yv;
}

// ---------------------------------------------------------------------------
// Kernel A: pure streaming. 4 voxels/thread. Writes default outputs for ALL
// voxels (seeds are overwritten by kernel B) + per-wave seed ballot bitmap.
__global__ __launch_bounds__(256)
void stream_kernel(const float4* __restrict__ x4,
                   const int4*  __restrict__ m4,
                   float* __restrict__ out,
                   unsigned long long* __restrict__ bitmap)
{
    int tid  = blockIdx.x * 256 + threadIdx.x;   // 0 .. TOT/4-1
    int idx4 = tid << 2;

    int w  = idx4 & (W_ - 1);
    int h  = (idx4 >> 9) & (H_ - 1);
    int t  = idx4 >> 18;
    int d  = t % D_;
    int bc = t / D_;
    int sp = idx4 - bc * DHW_;

    float4 xv = x4[tid];
    int4   mv = m4[tid];

    // y_max default = x
    *(float4*)(out + BC_ * 3 * DHW_ + idx4) = xv;

    // coords defaults: cs=d, cx=w.., cy=h
    float fd = (float)d, fh = (float)h;
    float4 csv = {fd, fd, fd, fd};
    float4 cxv = {(float)w, (float)(w + 1), (float)(w + 2), (float)(w + 3)};
    float4 cyv = {fh, fh, fh, fh};
    float* ob = out + (bc * 3) * DHW_ + sp;
    *(float4*)(ob)            = csv;
    *(float4*)(ob + DHW_)     = cxv;
    *(float4*)(ob + 2 * DHW_) = cyv;

    // Seed bitmap: wave g covers voxels [g*256, g*256+256); word j bit l
    // corresponds to voxel g*256 + l*4 + j.
    unsigned long long b0 = __ballot(mv.x != 0);
    unsigned long long b1 = __ballot(mv.y != 0);
    unsigned long long b2 = __ballot(mv.z != 0);
    unsigned long long b3 = __ballot(mv.w != 0);
    int g    = tid >> 6;
    int lane = threadIdx.x & 63;
    if (lane == 0) {
        unsigned long long* bp = bitmap + (size_t)g * 4;
        bp[0] = b0; bp[1] = b1; bp[2] = b2; bp[3] = b3;
    }
}

// ---------------------------------------------------------------------------
// Kernel B: sparse walk. One wave per 256-voxel group; waves with no seeds
// read 32 B and exit (wave-uniform branch).
__global__ __launch_bounds__(256)
void sparse_kernel(const float* __restrict__ x,
                   float* __restrict__ out,
                   const unsigned long long* __restrict__ bitmap)
{
    int g    = (blockIdx.x * 256 + threadIdx.x) >> 6;   // global wave id
    int lane = threadIdx.x & 63;

    const unsigned long long* bp = bitmap + (size_t)g * 4;
    unsigned long long b0 = bp[0], b1 = bp[1], b2 = bp[2], b3 = bp[3];
    if ((b0 | b1 | b2 | b3) == 0ULL) return;

    int base = g << 8;
    if ((b0 >> lane) & 1ULL) walk_and_write(x, out, base + lane * 4 + 0);
    if ((b1 >> lane) & 1ULL) walk_and_write(x, out, base + lane * 4 + 1);
    if ((b2 >> lane) & 1ULL) walk_and_write(x, out, base + lane * 4 + 2);
    if ((b3 >> lane) & 1ULL) walk_and_write(x, out, base + lane * 4 + 3);
}

// ---------------------------------------------------------------------------
// Fallback single kernel (round-2 correct version) if ws_size is too small.
__global__ __launch_bounds__(256)
void fused_kernel(const float* __restrict__ x,
                  const int* __restrict__ mask,
                  float* __restrict__ out)
{
    int idx = blockIdx.x * 256 + threadIdx.x;
    if (idx >= TOT_) return;
    int w  = idx & (W_ - 1);
    int h  = (idx >> 9) & (H_ - 1);
    int t  = idx >> 18;
    int d  = t % D_;
    int bc = t / D_;
    int sp = idx - bc * DHW_;
    if (mask[idx] != 0) {
        walk_and_write(x, out, idx);
    } else {
        out[(bc * 3 + 0) * DHW_ + sp] = (float)d;
        out[(bc * 3 + 1) * DHW_ + sp] = (float)w;
        out[(bc * 3 + 2) * DHW_ + sp] = (float)h;
        out[BC_ * 3 * DHW_ + idx]     = x[idx];
    }
}

extern "C" void kernel_launch(void* const* d_in, const int* in_sizes, int n_in,
                              void* d_out, int out_size, void* d_ws, size_t ws_size,
                              hipStream_t stream) {
    const float* x    = (const float*)d_in[0];
    const int*   mask = (const int*)d_in[1];
    float*       out  = (float*)d_out;

    if (ws_size >= BITMAP_BYTES_) {
        unsigned long long* bitmap = (unsigned long long*)d_ws;
        int blocksA = (TOT_ / 4) / 256;          // 12288
        stream_kernel<<<blocksA, 256, 0, stream>>>(
            (const float4*)x, (const int4*)mask, out, bitmap);
        int blocksB = (NWAVES_ * 64) / 256;      // 12288
        sparse_kernel<<<blocksB, 256, 0, stream>>>(x, out, bitmap);
    } else {
        int blocks = (TOT_ + 255) / 256;
        fused_kernel<<<blocks, 256, 0, stream>>>(x, mask, out);
    }
}

// Round 4
// 282.978 us; speedup vs baseline: 1.0680x; 1.0680x over previous
//
#include <hip/hip_runtime.h>

// Reference numpy/jnp math is UNFUSED IEEE f32 — disable FMA contraction so
// the catastrophically-cancelled det (compared against EPS=1e-7) and the
// 1/det-scaled shifts are bit-identical to the reference.
#pragma clang fp contract(off)

// Problem constants (from setup_inputs): B=2, C=4, D=6, H=512, W=512, f32.
constexpr int B_ = 2, C_ = 4, D_ = 6, H_ = 512, W_ = 512;
constexpr int HW_  = H_ * W_;        // 262144
constexpr int DHW_ = D_ * HW_;       // 1572864
constexpr int BC_  = B_ * C_;        // 8
constexpr int TOT_ = BC_ * DHW_;     // 12582912

#define EPS_ 1e-7f
#define MAX_SHIFT_ 0.6f
#define BONUS_ 10.0f
#define N_ITERS_ 5

// ---------------------------------------------------------------------------
// 3x3x3 quadratic-fit Cramer solve; p points at the (interior) center voxel.
// Op ordering mirrors the reference exactly (f32, no contraction).
__device__ __forceinline__ void solve3(const float* __restrict__ p,
                                       float& sx, float& sy, float& ss,
                                       float& gds, bool& sol)
{
    #pragma clang fp contract(off)
    float c    = p[0];
    float xp   = p[1],          xm   = p[-1];
    float yp   = p[W_],         ym   = p[-W_];
    float spv  = p[HW_],        smv  = p[-HW_];
    float xpyp = p[W_ + 1],     xmyp = p[W_ - 1];
    float xpym = p[-W_ + 1],    xmym = p[-W_ - 1];
    float xpsp = p[HW_ + 1],    xmsp = p[HW_ - 1];
    float xpsm = p[-HW_ + 1],   xmsm = p[-HW_ - 1];
    float ypsp = p[HW_ + W_],   ymsp = p[HW_ - W_];
    float ypsm = p[-HW_ + W_],  ymsm = p[-HW_ - W_];

    float gx = 0.5f * (xp - xm);
    float gy = 0.5f * (yp - ym);
    float gs = 0.5f * (spv - smv);
    float dxx = xp - 2.0f * c + xm;
    float dyy = yp - 2.0f * c + ym;
    float dss = spv - 2.0f * c + smv;
    float dxy = 0.25f * (xpyp - xmyp - xpym + xmym);
    float dxs = 0.25f * (xpsp - xmsp - xpsm + xmsm);
    float dys = 0.25f * (ypsp - ymsp - ypsm + ymsm);

    float cf00 = dyy * dss - dys * dys;
    float cf01 = dxy * dss - dys * dxs;
    float cf02 = dxy * dys - dyy * dxs;
    float det  = dxx * cf00 - dxy * cf01 + dxs * cf02;
    sol = fabsf(det) > EPS_;
    float sd = sol ? det : 1.0f;
    float r0 = -gx, r1 = -gy, r2 = -gs;
    sx = (r0 * cf00 - dxy * (r1 * dss - dys * r2) + dxs * (r1 * dys - dyy * r2)) / sd;
    sy = (dxx * (r1 * dss - dys * r2) - r0 * cf01 + dxs * (dxy * r2 - r1 * dxs)) / sd;
    ss = (dxx * (dyy * r2 - r1 * dys) - dxy * (dxy * r2 - r1 * dxs) + r0 * cf02) / sd;
    gds = gx * sx + gy * sy + gs * ss;
}

// Full reference walk + output write for one seed voxel (xc = x[idx] already
// loaded). Writes go to the SEED position, owned by the calling thread.
__device__ __forceinline__ void walk_and_write(const float* __restrict__ x,
                                               float* __restrict__ out,
                                               int idx, float xc)
{
    #pragma clang fp contract(off)
    int w  = idx & (W_ - 1);
    int h  = (idx >> 9) & (H_ - 1);
    int t  = idx >> 18;
    int d  = t % D_;
    int bc = t / D_;
    int sp = idx - bc * DHW_;
    const float* xb = x + bc * DHW_;

    int dd = 0, dh = 0, dwo = 0;
    bool valid = true;
    float shx = 0.0f, shy = 0.0f, shs = 0.0f, gk = 0.0f;

    #pragma unroll 1
    for (int it = 0; it < N_ITERS_; ++it) {
        int di = min(max(d + dd, 1), D_ - 2);
        int hi = min(max(h + dh, 1), H_ - 2);
        int wi = min(max(w + dwo, 1), W_ - 2);
        const float* p = xb + di * HW_ + hi * W_ + wi;

        float sx, sy, ssv, gds; bool sol;
        solve3(p, sx, sy, ssv, gds, sol);

        valid = valid && sol;
        float vf = valid ? 1.0f : 0.0f;
        shx = sx * vf;
        shy = sy * vf;
        shs = ssv * vf;
        gk  = gds * vf;

        int stx = (shx > MAX_SHIFT_) ? 1 : ((shx < -MAX_SHIFT_) ? -1 : 0);
        int sty = (shy > MAX_SHIFT_) ? 1 : ((shy < -MAX_SHIFT_) ? -1 : 0);
        int sts = (shs > MAX_SHIFT_) ? 1 : ((shs < -MAX_SHIFT_) ? -1 : 0);
        dwo += stx;
        dh  += sty;
        dd  += sts;
        valid = valid && (abs(dd) <= 1) && (abs(dh) <= 1) && (abs(dwo) <= 1);
    }

    int di = min(max(d + dd, 1), D_ - 2);
    int hi = min(max(h + dh, 1), H_ - 2);
    int wi = min(max(w + dwo, 1), W_ - 2);
    float cur = xb[di * HW_ + hi * W_ + wi];

    float refined = valid ? (cur + 0.5f * gk) : xc;
    float yv = refined + BONUS_;               // nms_mask true at seeds
    float cs = valid ? ((float)(d + dd) + shs) : (float)d;
    float cx = valid ? ((float)(w + dwo) + shx) : (float)w;
    float cy = valid ? ((float)(h + dh) + shy) : (float)h;

    out[(bc * 3 + 0) * DHW_ + sp] = cs;
    out[(bc * 3 + 1) * DHW_ + sp] = cx;
    out[(bc * 3 + 2) * DHW_ + sp] = cy;
    out[BC_ * 3 * DHW_ + idx]     = yv;
}

// ---------------------------------------------------------------------------
// One fused pass: 4 voxels/thread. Vectorized default outputs for ALL voxels,
// then a wave-uniform ballot skip; seed lanes run the walk inline and
// overwrite their own voxel's outputs (same thread → program-order safe).
__global__ __launch_bounds__(256)
void AdaptiveQuadInterp3d_kernel(const float4* __restrict__ x4,
                                 const int4*  __restrict__ m4,
                                 float* __restrict__ out)
{
    int tid  = blockIdx.x * 256 + threadIdx.x;   // 0 .. TOT/4-1
    int idx4 = tid << 2;

    int w  = idx4 & (W_ - 1);
    int h  = (idx4 >> 9) & (H_ - 1);
    int t  = idx4 >> 18;
    int d  = t % D_;
    int bc = t / D_;
    int sp = idx4 - bc * DHW_;

    float4 xv = x4[tid];
    int4   mv = m4[tid];

    // y_max default = x
    *(float4*)(out + BC_ * 3 * DHW_ + idx4) = xv;

    // coords defaults: cs=d, cx=w.., cy=h
    float fd = (float)d, fh = (float)h;
    float4 csv = {fd, fd, fd, fd};
    float4 cxv = {(float)w, (float)(w + 1), (float)(w + 2), (float)(w + 3)};
    float4 cyv = {fh, fh, fh, fh};
    float* ob = out + (bc * 3) * DHW_ + sp;
    *(float4*)(ob)            = csv;
    *(float4*)(ob + DHW_)     = cxv;
    *(float4*)(ob + 2 * DHW_) = cyv;

    // Wave-uniform skip: 0.999^256 = 77% of waves have zero seeds.
    bool any_lane = (mv.x | mv.y | mv.z | mv.w) != 0;
    if (__ballot(any_lane) == 0ULL) return;

    const float* x = (const float*)x4;
    if (mv.x != 0) walk_and_write(x, out, idx4 + 0, xv.x);
    if (mv.y != 0) walk_and_write(x, out, idx4 + 1, xv.y);
    if (mv.z != 0) walk_and_write(x, out, idx4 + 2, xv.z);
    if (mv.w != 0) walk_and_write(x, out, idx4 + 3, xv.w);
}

extern "C" void kernel_launch(void* const* d_in, const int* in_sizes, int n_in,
                              void* d_out, int out_size, void* d_ws, size_t ws_size,
                              hipStream_t stream) {
    const float* x    = (const float*)d_in[0];
    const int*   mask = (const int*)d_in[1];
    float*       out  = (float*)d_out;

    int blocks = (TOT_ / 4) / 256;   // 12288
    AdaptiveQuadInterp3d_kernel<<<blocks, 256, 0, stream>>>(
        (const float4*)x, (const int4*)mask, out);
}